// Round 4
// baseline (305.894 us; speedup 1.0000x reference)
//
#include <hip/hip_runtime.h>
#include <stdint.h>

#define B_N 16384
#define H_N 256
#define IN_W 258
#define GX_N 70
#define GY_N 70
#define SW_N 2
#define KK_N 25

typedef __bf16 bf16x8 __attribute__((ext_vector_type(8)));
typedef __bf16 bf16x4 __attribute__((ext_vector_type(4)));
typedef __bf16 bf16x2 __attribute__((ext_vector_type(2)));
typedef float f32x4 __attribute__((ext_vector_type(4)));
typedef float f32x2 __attribute__((ext_vector_type(2)));

#define AS1 __attribute__((address_space(1)))
#define AS3 __attribute__((address_space(3)))

static __device__ __forceinline__ void gload16(const void* g, void* l) {
    __builtin_amdgcn_global_load_lds((const AS1 uint32_t*)g, (AS3 uint32_t*)l, 16, 0, 0);
}

// ---- ws layout (bf16 elements) ----
// AB    at 0        : [16384][512]  ([feat|hid])            16 MB
// wfull at 8388608  : [1024][512]   rows j=c*256+col, c in {r,i,s,n};
//                     k<256 -> wih[base_c+col][k], k>=256 -> whh[base_c+col][k-256]
//                     base_c = {0,256,768,512}
// woutB at 8912896  : [256][512]
// comb  at 9043968  : [16384][512]  ([mix|q])               16 MB
// ugsg  at 17432576 : [16384][256][2] (ug,sg interleaved)   16 MB
#define E_AB   8388608ULL
#define E_WF   8912896ULL
#define E_WOUT 9043968ULL
#define E_COMB 9043968ULL
#define E_UGSG 17432576ULL

__global__ __launch_bounds__(256) void cast_kernel(
    const float* __restrict__ in_t, const float* __restrict__ hid,
    const float* __restrict__ wih, const float* __restrict__ whh,
    const float* __restrict__ wout, __bf16* __restrict__ dst)
{
    size_t g = (size_t)blockIdx.x * blockDim.x + threadIdx.x;
    size_t stride = (size_t)gridDim.x * blockDim.x;
    for (size_t e = g * 4; e < E_WOUT; e += stride * 4) {
        bf16x4 o;
        if (e < E_AB) {
            size_t row = e >> 9;
            size_t c = e & 511;
            if (c < 256) {
                // in_t row stride 258 f32 = 1032 B (8B-aligned); c%4==0 -> 8B-aligned
                const f32x2* s2 = reinterpret_cast<const f32x2*>(in_t + row * IN_W + c);
                f32x2 a = s2[0], b = s2[1];
                o.x = (__bf16)a.x; o.y = (__bf16)a.y;
                o.z = (__bf16)b.x; o.w = (__bf16)b.y;
            } else {
                f32x4 v = *reinterpret_cast<const f32x4*>(hid + row * 256 + (c - 256));
                o.x = (__bf16)v.x; o.y = (__bf16)v.y;
                o.z = (__bf16)v.z; o.w = (__bf16)v.w;
            }
        } else if (e < E_WF) {
            size_t off = e - E_AB;
            size_t j = off >> 9;       // 0..1023
            size_t k = off & 511;
            size_t c = j >> 8;         // 0..3
            size_t col = j & 255;
            size_t base = (c == 0) ? 0 : (c == 1) ? 256 : (c == 2) ? 768 : 512;
            const float* srcm = (k < 256) ? wih : whh;
            f32x4 v = *reinterpret_cast<const f32x4*>(srcm + (base + col) * 256 + (k & 255));
            o.x = (__bf16)v.x; o.y = (__bf16)v.y;
            o.z = (__bf16)v.z; o.w = (__bf16)v.w;
        } else {
            f32x4 v = *reinterpret_cast<const f32x4*>(wout + (e - E_WF));
            o.x = (__bf16)v.x; o.y = (__bf16)v.y;
            o.z = (__bf16)v.z; o.w = (__bf16)v.w;
        }
        *reinterpret_cast<bf16x4*>(dst + e) = o;
    }
}

// Fused gates GEMM, K=512 concat form. 2-phase double-buffered pipeline
// (round-2 proven structure): stage(next tile) issued BEFORE compute(current),
// one __syncthreads per K-step. launch_bounds(256,3): LDS 48KB -> 3 blocks/CU
// (144<=160KB), VGPR 120<=170 -> cross-block implicit overlap (m114) hides
// the per-step vmcnt(0) barrier drain.
// block = 256 rows x 128 cols (32 hcols x 4 gates), 4 waves; wave owns
// 64x128: 32 MFMA / 12 ds_read_b128 per 32-K step.
__global__ __launch_bounds__(256, 3) void gates_gemm(
    const __bf16* __restrict__ AB, const __bf16* __restrict__ wfull,
    const float* __restrict__ b_ih, const float* __restrict__ b_hh,
    __bf16* __restrict__ comb, __bf16* __restrict__ ugsg)
{
    __shared__ __bf16 ldsA[2][8192];   // [buf][seg(4)][row(256)][8]
    __shared__ __bf16 ldsB[2][4096];   // [buf][seg(4)][brow(128)][8]
    const int t = threadIdx.x;
    const int lane = t & 63, w = t >> 6;
    const int lr = lane & 15, seg = lane >> 4;
    const int rb = blockIdx.x * 256;
    const int h0 = blockIdx.y * 32;

    // staging map:
    // A: thread t owns row rb+t, all 4 k-segs (chunks at lds elem t*8 + i*2048)
    // B: thread t owns brow = t&127 (c=(t&127)>>5, col32=t&31), segs {t>>7, t>>7+2}
    const __bf16* gAt = AB + (size_t)(rb + t) * 512;
    const int bc = (t & 127) >> 5;
    const int bcol = t & 31;
    const __bf16* gBt = wfull + (size_t)(bc * 256 + h0 + bcol) * 512 + ((t >> 7) << 3);
    __bf16* lA0 = &ldsA[0][t * 8];
    __bf16* lA1 = &ldsA[1][t * 8];
    __bf16* lB0 = &ldsB[0][t * 8];
    __bf16* lB1 = &ldsB[1][t * 8];

    f32x4 acc[4][6], accni[4][2], accnh[4][2];
#pragma unroll
    for (int rh = 0; rh < 4; rh++) {
#pragma unroll
        for (int cn = 0; cn < 6; cn++) acc[rh][cn] = (f32x4){0.f, 0.f, 0.f, 0.f};
        accni[rh][0] = (f32x4){0.f, 0.f, 0.f, 0.f};
        accni[rh][1] = (f32x4){0.f, 0.f, 0.f, 0.f};
        accnh[rh][0] = (f32x4){0.f, 0.f, 0.f, 0.f};
        accnh[rh][1] = (f32x4){0.f, 0.f, 0.f, 0.f};
    }

    // prologue: stage tile 0 into buf 0
    gload16(gAt + 0, lA0);
    gload16(gAt + 8, lA0 + 2048);
    gload16(gAt + 16, lA0 + 4096);
    gload16(gAt + 24, lA0 + 6144);
    gload16(gBt + 0, lB0);
    gload16(gBt + 16, lB0 + 2048);
    __syncthreads();   // implicit vmcnt(0)

#pragma unroll 1
    for (int tt = 0; tt < 16; tt++) {
        const int cur = tt & 1;
        if (tt < 15) {   // issue next tile's stage BEFORE compute
            const int kn = (tt + 1) * 32;
            __bf16* la = cur ? lA0 : lA1;
            __bf16* lb = cur ? lB0 : lB1;
            gload16(gAt + kn, la);
            gload16(gAt + kn + 8, la + 2048);
            gload16(gAt + kn + 16, la + 4096);
            gload16(gAt + kn + 24, la + 6144);
            gload16(gBt + kn, lb);
            gload16(gBt + kn + 16, lb + 2048);
        }
        const __bf16* cA = ldsA[cur];
        const __bf16* cB = ldsB[cur];
        bf16x8 af[4];
#pragma unroll
        for (int rh = 0; rh < 4; rh++)
            af[rh] = *reinterpret_cast<const bf16x8*>(cA + seg * 2048 + (w * 64 + rh * 16 + lr) * 8);
#pragma unroll
        for (int cn = 0; cn < 6; cn++) {
            bf16x8 bb = *reinterpret_cast<const bf16x8*>(cB + seg * 1024 + (cn * 16 + lr) * 8);
#pragma unroll
            for (int rh = 0; rh < 4; rh++)
                acc[rh][cn] = __builtin_amdgcn_mfma_f32_16x16x32_bf16(af[rh], bb, acc[rh][cn], 0, 0, 0);
        }
        bf16x8 b6 = *reinterpret_cast<const bf16x8*>(cB + seg * 1024 + (96 + lr) * 8);
        bf16x8 b7 = *reinterpret_cast<const bf16x8*>(cB + seg * 1024 + (112 + lr) * 8);
        if (tt < 8) {
#pragma unroll
            for (int rh = 0; rh < 4; rh++) {
                accni[rh][0] = __builtin_amdgcn_mfma_f32_16x16x32_bf16(af[rh], b6, accni[rh][0], 0, 0, 0);
                accni[rh][1] = __builtin_amdgcn_mfma_f32_16x16x32_bf16(af[rh], b7, accni[rh][1], 0, 0, 0);
            }
        } else {
#pragma unroll
            for (int rh = 0; rh < 4; rh++) {
                accnh[rh][0] = __builtin_amdgcn_mfma_f32_16x16x32_bf16(af[rh], b6, accnh[rh][0], 0, 0, 0);
                accnh[rh][1] = __builtin_amdgcn_mfma_f32_16x16x32_bf16(af[rh], b7, accnh[rh][1], 0, 0, 0);
            }
        }
        __syncthreads();   // vmcnt(0): next tile landed; lgkm: reads done -> buf reusable
    }

#pragma unroll
    for (int hh = 0; hh < 2; hh++) {
        const int col = h0 + hh * 16 + lr;
        const float br_ = b_ih[col] + b_hh[col];
        const float bi_ = b_ih[col + 256] + b_hh[col + 256];
        const float bs_ = b_ih[col + 768] + b_hh[col + 768];
        const float bni = b_ih[col + 512];
        const float bnh = b_hh[col + 512];
#pragma unroll
        for (int rh = 0; rh < 4; rh++) {
#pragma unroll
            for (int r = 0; r < 4; r++) {
                const int row = rb + w * 64 + rh * 16 + seg * 4 + r;
                float sr = acc[rh][hh][r] + br_;
                float si = acc[rh][2 + hh][r] + bi_;
                float ss = acc[rh][4 + hh][r] + bs_;
                float vni = accni[rh][hh][r] + bni;
                float vnh = accnh[rh][hh][r] + bnh;
                float rg = 1.f / (1.f + __expf(-sr));
                float ug = 1.f / (1.f + __expf(-si));
                float sg = 1.f / (1.f + __expf(-ss));
                float ng = tanhf(vni + rg * vnh);
                comb[(size_t)row * 512 + 256 + col] = (__bf16)ng;
                bf16x2 us;
                us.x = (__bf16)ug;
                us.y = (__bf16)sg;
                *reinterpret_cast<bf16x2*>(ugsg + ((size_t)row * 256 + col) * 2) = us;
            }
        }
    }
}

// Attention: one wave per row, online softmax, float4 per lane (h = 4*lane..4*lane+3).
__global__ __launch_bounds__(256) void attn_kernel(
    const float* __restrict__ in_t, const float* __restrict__ memory,
    __bf16* __restrict__ comb)
{
    const int w = threadIdx.x >> 6;
    const int lane = threadIdx.x & 63;
    const int b = blockIdx.x * 4 + w;
    const float* row_in = in_t + (size_t)b * IN_W;
    int gx = (int)row_in[256] + SW_N;
    int gy = (int)row_in[257] + SW_N;
    gx = min(max(gx, 0), GX_N - 1);
    gy = min(max(gy, 0), GY_N - 1);

    bf16x4 qb = *reinterpret_cast<const bf16x4*>(comb + (size_t)b * 512 + 256 + lane * 4);
    float q0 = (float)qb.x, q1 = (float)qb.y, q2 = (float)qb.z, q3 = (float)qb.w;

    float m = -INFINITY, d = 0.f;
    float o0 = 0.f, o1 = 0.f, o2 = 0.f, o3 = 0.f;
#pragma unroll
    for (int k = 0; k < KK_N; k++) {
        int i = k / 5, j = k % 5;
        int xi = min(max(gx + i - SW_N, 0), GX_N - 1);
        int yj = min(max(gy + j - SW_N, 0), GY_N - 1);
        const f32x4* cp = reinterpret_cast<const f32x4*>(memory + ((size_t)xi * GY_N + yj) * H_N);
        f32x4 v = cp[lane];
        float p = q0 * v.x + q1 * v.y + q2 * v.z + q3 * v.w;
        for (int off = 32; off; off >>= 1) p += __shfl_xor(p, off, 64);
        float a = (p == 0.f) ? -INFINITY : p;
        float mn = fmaxf(m, a);
        if (mn != -INFINITY) {
            float alpha = __expf(m - mn);   // m=-inf -> 0
            float e = __expf(a - mn);       // a=-inf -> 0
            d = d * alpha + e;
            o0 = o0 * alpha + e * v.x;
            o1 = o1 * alpha + e * v.y;
            o2 = o2 * alpha + e * v.z;
            o3 = o3 * alpha + e * v.w;
            m = mn;
        }
    }
    float inv = (d != 0.f) ? 1.f / d : 0.f;
    bf16x4 ob;
    ob.x = (__bf16)(o0 * inv);
    ob.y = (__bf16)(o1 * inv);
    ob.z = (__bf16)(o2 * inv);
    ob.w = (__bf16)(o3 * inv);
    *reinterpret_cast<bf16x4*>(comb + (size_t)b * 512 + lane * 4) = ob;
}

// Output GEMM (K=512) + tanh + final blend. 2-phase double-buffered
// pipeline (round-2 structure, tile 128x64, 4 waves, wave = 32x64).
// grid = (128 row-tiles, 4 col-tiles): id%8 = bx%8 -> XCD affinity.
__global__ __launch_bounds__(256, 4) void out_gemm(
    const __bf16* __restrict__ comb, const __bf16* __restrict__ woB,
    const float* __restrict__ b_out, const __bf16* __restrict__ ugsg,
    const float* __restrict__ hidden, float* __restrict__ out)
{
    __shared__ __bf16 ldsA[2][4096];   // [buf][seg(4)][row(128)][8]
    __shared__ __bf16 ldsB[2][2048];   // [buf][seg(4)][brow(64)][8]
    const int t = threadIdx.x;
    const int lane = t & 63, w = t >> 6;
    const int lr = lane & 15, seg = lane >> 4;
    const int rb = blockIdx.x * 128;
    const int n0 = blockIdx.y * 64;

    const __bf16* gAt = comb + (size_t)(rb + (t & 127)) * 512 + ((t >> 7) << 3);
    const __bf16* gBt = woB + (size_t)(n0 + (t & 63)) * 512 + ((t >> 6) << 3);
    __bf16* lA0 = &ldsA[0][t * 8];
    __bf16* lA1 = &ldsA[1][t * 8];
    __bf16* lB0 = &ldsB[0][t * 8];
    __bf16* lB1 = &ldsB[1][t * 8];

    f32x4 acc[2][4];
#pragma unroll
    for (int rh = 0; rh < 2; rh++)
#pragma unroll
        for (int ct = 0; ct < 4; ct++) acc[rh][ct] = (f32x4){0.f, 0.f, 0.f, 0.f};

    // prologue: tile 0 -> buf 0
    gload16(gAt + 0, lA0);
    gload16(gAt + 16, lA0 + 2048);
    gload16(gBt + 0, lB0);
    __syncthreads();

#pragma unroll 1
    for (int tt = 0; tt < 16; tt++) {
        const int cur = tt & 1;
        if (tt < 15) {
            const int kn = (tt + 1) * 32;
            __bf16* la = cur ? lA0 : lA1;
            __bf16* lb = cur ? lB0 : lB1;
            gload16(gAt + kn, la);
            gload16(gAt + kn + 16, la + 2048);
            gload16(gBt + kn, lb);
        }
        const __bf16* cA = ldsA[cur];
        const __bf16* cB = ldsB[cur];
        bf16x8 af[2];
#pragma unroll
        for (int rh = 0; rh < 2; rh++)
            af[rh] = *reinterpret_cast<const bf16x8*>(cA + seg * 1024 + (w * 32 + rh * 16 + lr) * 8);
#pragma unroll
        for (int ct = 0; ct < 4; ct++) {
            bf16x8 bb = *reinterpret_cast<const bf16x8*>(cB + seg * 512 + (ct * 16 + lr) * 8);
#pragma unroll
            for (int rh = 0; rh < 2; rh++)
                acc[rh][ct] = __builtin_amdgcn_mfma_f32_16x16x32_bf16(af[rh], bb, acc[rh][ct], 0, 0, 0);
        }
        __syncthreads();
    }

#pragma unroll
    for (int ct = 0; ct < 4; ct++) {
        int col = n0 + ct * 16 + lr;
        float bo = b_out[col];
#pragma unroll
        for (int rh = 0; rh < 2; rh++) {
#pragma unroll
            for (int r = 0; r < 4; r++) {
                int row = rb + w * 32 + rh * 16 + seg * 4 + r;
                size_t idx = (size_t)row * 256 + col;
                float acs = tanhf(acc[rh][ct][r] + bo);
                float ng = (float)comb[(size_t)row * 512 + 256 + col];
                bf16x2 us = *reinterpret_cast<const bf16x2*>(ugsg + idx * 2);
                float ug = (float)us.x, sg = (float)us.y;
                float curr = ng + sg * acs;
                out[idx] = curr + ug * (hidden[idx] - curr);
            }
        }
    }
}

extern "C" void kernel_launch(void* const* d_in, const int* in_sizes, int n_in,
                              void* d_out, int out_size, void* d_ws, size_t ws_size,
                              hipStream_t stream) {
    const float* input_t = (const float*)d_in[0];
    const float* hidden  = (const float*)d_in[1];
    const float* w_ih    = (const float*)d_in[2];
    const float* b_ih    = (const float*)d_in[3];
    const float* w_hh    = (const float*)d_in[4];
    const float* b_hh    = (const float*)d_in[5];
    const float* w_out   = (const float*)d_in[6];
    const float* b_out   = (const float*)d_in[7];
    const float* memory  = (const float*)d_in[8];
    float* out = (float*)d_out;

    __bf16* base  = (__bf16*)d_ws;
    __bf16* AB    = base;
    __bf16* wfull = base + E_AB;
    __bf16* woutB = base + E_WF;
    __bf16* comb  = base + E_COMB;
    __bf16* ugsg  = base + E_UGSG;

    cast_kernel<<<4096, 256, 0, stream>>>(input_t, hidden, w_ih, w_hh, w_out, base);
    gates_gemm<<<dim3(64, 8), 256, 0, stream>>>(AB, wfull, b_ih, b_hh, comb, ugsg);
    attn_kernel<<<4096, 256, 0, stream>>>(input_t, memory, comb);
    out_gemm<<<dim3(128, 4), 256, 0, stream>>>(comb, woutB, b_out, ugsg, hidden, out);
}

// Round 5
// 253.634 us; speedup vs baseline: 1.2060x; 1.2060x over previous
//
#include <hip/hip_runtime.h>
#include <stdint.h>

#define B_N 16384
#define H_N 256
#define IN_W 258
#define GX_N 70
#define GY_N 70
#define SW_N 2
#define KK_N 25

typedef __bf16 bf16x8 __attribute__((ext_vector_type(8)));
typedef __bf16 bf16x4 __attribute__((ext_vector_type(4)));
typedef __bf16 bf16x2 __attribute__((ext_vector_type(2)));
typedef float f32x4 __attribute__((ext_vector_type(4)));
typedef float f32x2 __attribute__((ext_vector_type(2)));

// ---- ws layout (bf16 elements) ----
// AB    at 0        : [16384][512]  ([feat|hid])            16 MB
// wfull at 8388608  : [1024][512]   rows j=c*256+col, c in {r,i,s,n};
//                     k<256 -> wih[base_c+col][k], k>=256 -> whh[base_c+col][k-256]
//                     base_c = {0,256,768,512}
// woutB at 8912896  : [256][512]
// comb  at 9043968  : [16384][512]  ([mix|q])               16 MB
// ugsg  at 17432576 : [16384][256][2] (ug,sg interleaved)   16 MB
#define E_AB   8388608ULL
#define E_WF   8912896ULL
#define E_WOUT 9043968ULL
#define E_COMB 9043968ULL
#define E_UGSG 17432576ULL

__global__ __launch_bounds__(256) void cast_kernel(
    const float* __restrict__ in_t, const float* __restrict__ hid,
    const float* __restrict__ wih, const float* __restrict__ whh,
    const float* __restrict__ wout, __bf16* __restrict__ dst)
{
    size_t g = (size_t)blockIdx.x * blockDim.x + threadIdx.x;
    size_t stride = (size_t)gridDim.x * blockDim.x;
    for (size_t e = g * 4; e < E_WOUT; e += stride * 4) {
        bf16x4 o;
        if (e < E_AB) {
            size_t row = e >> 9;
            size_t c = e & 511;
            if (c < 256) {
                // in_t row stride 258 f32 = 1032 B (8B-aligned); c%4==0 -> 8B-aligned
                const f32x2* s2 = reinterpret_cast<const f32x2*>(in_t + row * IN_W + c);
                f32x2 a = s2[0], b = s2[1];
                o.x = (__bf16)a.x; o.y = (__bf16)a.y;
                o.z = (__bf16)b.x; o.w = (__bf16)b.y;
            } else {
                f32x4 v = *reinterpret_cast<const f32x4*>(hid + row * 256 + (c - 256));
                o.x = (__bf16)v.x; o.y = (__bf16)v.y;
                o.z = (__bf16)v.z; o.w = (__bf16)v.w;
            }
        } else if (e < E_WF) {
            size_t off = e - E_AB;
            size_t j = off >> 9;       // 0..1023
            size_t k = off & 511;
            size_t c = j >> 8;         // 0..3
            size_t col = j & 255;
            size_t base = (c == 0) ? 0 : (c == 1) ? 256 : (c == 2) ? 768 : 512;
            const float* srcm = (k < 256) ? wih : whh;
            f32x4 v = *reinterpret_cast<const f32x4*>(srcm + (base + col) * 256 + (k & 255));
            o.x = (__bf16)v.x; o.y = (__bf16)v.y;
            o.z = (__bf16)v.z; o.w = (__bf16)v.w;
        } else {
            f32x4 v = *reinterpret_cast<const f32x4*>(wout + (e - E_WF));
            o.x = (__bf16)v.x; o.y = (__bf16)v.y;
            o.z = (__bf16)v.z; o.w = (__bf16)v.w;
        }
        *reinterpret_cast<bf16x4*>(dst + e) = o;
    }
}

// Fused gates GEMM, K=512 concat form. DIRECT-FROM-GLOBAL fragments:
// operands are L2/LLC-resident (FETCH 12.5MB < |AB|), so no LDS, no
// barriers, no staging. Per wave-step: 4 A-frag + 8 B-frag 16B loads
// (lanes cover 16 rows x 64B contiguous -> full L2 sectors) + 32 MFMA.
// K-loop fully unrolled: compiler software-pipelines loads freely.
// NO second launch_bounds arg: (256,N) caps VGPR at ~256/N (measured:
// (256,2)->120, (256,3)->84) and spills the 160-VGPR accumulator set
// (round-4 counter evidence: WRITE_SIZE 34->364MB = scratch).
// block = 256 rows x 128 cols (32 hcols x 4 gates), 4 waves; wave owns
// 64x128. grid (64 row-tiles, 8 h-tiles): XCD = bx%8 -> the 8 col-blocks
// of a row-tile share an XCD -> A-tile read once per XCD L2.
__global__ __launch_bounds__(256) void gates_gemm(
    const __bf16* __restrict__ AB, const __bf16* __restrict__ wfull,
    const float* __restrict__ b_ih, const float* __restrict__ b_hh,
    __bf16* __restrict__ comb, __bf16* __restrict__ ugsg)
{
    const int t = threadIdx.x;
    const int lane = t & 63, w = t >> 6;
    const int lr = lane & 15, seg = lane >> 4;
    const int rb = blockIdx.x * 256;
    const int h0 = blockIdx.y * 32;

    // A frag (16x16x32 layout): row = rb + w*64 + rh*16 + lr, k = kt + seg*8
    const __bf16* pA = AB + (size_t)(rb + w * 64 + lr) * 512 + seg * 8;
    // B frag: wfull row = c*256 + h0 + hh*16 + lr, k = kt + seg*8
    const __bf16* pB = wfull + (size_t)(h0 + lr) * 512 + seg * 8;

    f32x4 acc[4][6], accni[4][2], accnh[4][2];
#pragma unroll
    for (int rh = 0; rh < 4; rh++) {
#pragma unroll
        for (int cn = 0; cn < 6; cn++) acc[rh][cn] = (f32x4){0.f, 0.f, 0.f, 0.f};
        accni[rh][0] = (f32x4){0.f, 0.f, 0.f, 0.f};
        accni[rh][1] = (f32x4){0.f, 0.f, 0.f, 0.f};
        accnh[rh][0] = (f32x4){0.f, 0.f, 0.f, 0.f};
        accnh[rh][1] = (f32x4){0.f, 0.f, 0.f, 0.f};
    }

#pragma unroll
    for (int tt = 0; tt < 16; tt++) {
        const int kt = tt * 32;
        bf16x8 af[4];
#pragma unroll
        for (int rh = 0; rh < 4; rh++)
            af[rh] = *reinterpret_cast<const bf16x8*>(pA + rh * (16 * 512) + kt);
#pragma unroll
        for (int cn = 0; cn < 6; cn++) {
            const int c = cn >> 1, hh = cn & 1;
            bf16x8 bb = *reinterpret_cast<const bf16x8*>(pB + (c * 256 + hh * 16) * 512 + kt);
#pragma unroll
            for (int rh = 0; rh < 4; rh++)
                acc[rh][cn] = __builtin_amdgcn_mfma_f32_16x16x32_bf16(af[rh], bb, acc[rh][cn], 0, 0, 0);
        }
        bf16x8 b6 = *reinterpret_cast<const bf16x8*>(pB + (768 + 0) * 512 + kt);
        bf16x8 b7 = *reinterpret_cast<const bf16x8*>(pB + (768 + 16) * 512 + kt);
        if (tt < 8) {   // compile-time under full unroll
#pragma unroll
            for (int rh = 0; rh < 4; rh++) {
                accni[rh][0] = __builtin_amdgcn_mfma_f32_16x16x32_bf16(af[rh], b6, accni[rh][0], 0, 0, 0);
                accni[rh][1] = __builtin_amdgcn_mfma_f32_16x16x32_bf16(af[rh], b7, accni[rh][1], 0, 0, 0);
            }
        } else {
#pragma unroll
            for (int rh = 0; rh < 4; rh++) {
                accnh[rh][0] = __builtin_amdgcn_mfma_f32_16x16x32_bf16(af[rh], b6, accnh[rh][0], 0, 0, 0);
                accnh[rh][1] = __builtin_amdgcn_mfma_f32_16x16x32_bf16(af[rh], b7, accnh[rh][1], 0, 0, 0);
            }
        }
    }

#pragma unroll
    for (int hh = 0; hh < 2; hh++) {
        const int col = h0 + hh * 16 + lr;
        const float br_ = b_ih[col] + b_hh[col];
        const float bi_ = b_ih[col + 256] + b_hh[col + 256];
        const float bs_ = b_ih[col + 768] + b_hh[col + 768];
        const float bni = b_ih[col + 512];
        const float bnh = b_hh[col + 512];
#pragma unroll
        for (int rh = 0; rh < 4; rh++) {
#pragma unroll
            for (int r = 0; r < 4; r++) {
                const int row = rb + w * 64 + rh * 16 + seg * 4 + r;
                float sr = acc[rh][hh][r] + br_;
                float si = acc[rh][2 + hh][r] + bi_;
                float ss = acc[rh][4 + hh][r] + bs_;
                float vni = accni[rh][hh][r] + bni;
                float vnh = accnh[rh][hh][r] + bnh;
                float rg = 1.f / (1.f + __expf(-sr));
                float ug = 1.f / (1.f + __expf(-si));
                float sg = 1.f / (1.f + __expf(-ss));
                float ng = tanhf(vni + rg * vnh);
                comb[(size_t)row * 512 + 256 + col] = (__bf16)ng;
                bf16x2 us;
                us.x = (__bf16)ug;
                us.y = (__bf16)sg;
                *reinterpret_cast<bf16x2*>(ugsg + ((size_t)row * 256 + col) * 2) = us;
            }
        }
    }
}

// Attention: one wave per row, online softmax, float4 per lane (h = 4*lane..4*lane+3).
__global__ __launch_bounds__(256) void attn_kernel(
    const float* __restrict__ in_t, const float* __restrict__ memory,
    __bf16* __restrict__ comb)
{
    const int w = threadIdx.x >> 6;
    const int lane = threadIdx.x & 63;
    const int b = blockIdx.x * 4 + w;
    const float* row_in = in_t + (size_t)b * IN_W;
    int gx = (int)row_in[256] + SW_N;
    int gy = (int)row_in[257] + SW_N;
    gx = min(max(gx, 0), GX_N - 1);
    gy = min(max(gy, 0), GY_N - 1);

    bf16x4 qb = *reinterpret_cast<const bf16x4*>(comb + (size_t)b * 512 + 256 + lane * 4);
    float q0 = (float)qb.x, q1 = (float)qb.y, q2 = (float)qb.z, q3 = (float)qb.w;

    float m = -INFINITY, d = 0.f;
    float o0 = 0.f, o1 = 0.f, o2 = 0.f, o3 = 0.f;
#pragma unroll
    for (int k = 0; k < KK_N; k++) {
        int i = k / 5, j = k % 5;
        int xi = min(max(gx + i - SW_N, 0), GX_N - 1);
        int yj = min(max(gy + j - SW_N, 0), GY_N - 1);
        const f32x4* cp = reinterpret_cast<const f32x4*>(memory + ((size_t)xi * GY_N + yj) * H_N);
        f32x4 v = cp[lane];
        float p = q0 * v.x + q1 * v.y + q2 * v.z + q3 * v.w;
        for (int off = 32; off; off >>= 1) p += __shfl_xor(p, off, 64);
        float a = (p == 0.f) ? -INFINITY : p;
        float mn = fmaxf(m, a);
        if (mn != -INFINITY) {
            float alpha = __expf(m - mn);   // m=-inf -> 0
            float e = __expf(a - mn);       // a=-inf -> 0
            d = d * alpha + e;
            o0 = o0 * alpha + e * v.x;
            o1 = o1 * alpha + e * v.y;
            o2 = o2 * alpha + e * v.z;
            o3 = o3 * alpha + e * v.w;
            m = mn;
        }
    }
    float inv = (d != 0.f) ? 1.f / d : 0.f;
    bf16x4 ob;
    ob.x = (__bf16)(o0 * inv);
    ob.y = (__bf16)(o1 * inv);
    ob.z = (__bf16)(o2 * inv);
    ob.w = (__bf16)(o3 * inv);
    *reinterpret_cast<bf16x4*>(comb + (size_t)b * 512 + lane * 4) = ob;
}

// Output GEMM (K=512) + tanh + final blend. Same direct-from-global
// structure: no LDS, no barriers, full K unroll.
// tile 128x64, 4 waves, wave = 32x64: per step 2 A-frag + 4 B-frag
// loads + 8 MFMA. grid (128 row-tiles, 4 col-tiles): XCD = bx%8.
__global__ __launch_bounds__(256) void out_gemm(
    const __bf16* __restrict__ comb, const __bf16* __restrict__ woB,
    const float* __restrict__ b_out, const __bf16* __restrict__ ugsg,
    const float* __restrict__ hidden, float* __restrict__ out)
{
    const int t = threadIdx.x;
    const int lane = t & 63, w = t >> 6;
    const int lr = lane & 15, seg = lane >> 4;
    const int rb = blockIdx.x * 128;
    const int n0 = blockIdx.y * 64;

    const __bf16* pA = comb + (size_t)(rb + w * 32 + lr) * 512 + seg * 8;
    const __bf16* pB = woB + (size_t)(n0 + lr) * 512 + seg * 8;

    f32x4 acc[2][4];
#pragma unroll
    for (int rh = 0; rh < 2; rh++)
#pragma unroll
        for (int ct = 0; ct < 4; ct++) acc[rh][ct] = (f32x4){0.f, 0.f, 0.f, 0.f};

#pragma unroll
    for (int tt = 0; tt < 16; tt++) {
        const int kt = tt * 32;
        bf16x8 af[2];
#pragma unroll
        for (int rh = 0; rh < 2; rh++)
            af[rh] = *reinterpret_cast<const bf16x8*>(pA + rh * (16 * 512) + kt);
#pragma unroll
        for (int ct = 0; ct < 4; ct++) {
            bf16x8 bb = *reinterpret_cast<const bf16x8*>(pB + ct * (16 * 512) + kt);
#pragma unroll
            for (int rh = 0; rh < 2; rh++)
                acc[rh][ct] = __builtin_amdgcn_mfma_f32_16x16x32_bf16(af[rh], bb, acc[rh][ct], 0, 0, 0);
        }
    }

#pragma unroll
    for (int ct = 0; ct < 4; ct++) {
        int col = n0 + ct * 16 + lr;
        float bo = b_out[col];
#pragma unroll
        for (int rh = 0; rh < 2; rh++) {
#pragma unroll
            for (int r = 0; r < 4; r++) {
                int row = rb + w * 32 + rh * 16 + seg * 4 + r;
                size_t idx = (size_t)row * 256 + col;
                float acs = tanhf(acc[rh][ct][r] + bo);
                float ng = (float)comb[(size_t)row * 512 + 256 + col];
                bf16x2 us = *reinterpret_cast<const bf16x2*>(ugsg + idx * 2);
                float ug = (float)us.x, sg = (float)us.y;
                float curr = ng + sg * acs;
                out[idx] = curr + ug * (hidden[idx] - curr);
            }
        }
    }
}

extern "C" void kernel_launch(void* const* d_in, const int* in_sizes, int n_in,
                              void* d_out, int out_size, void* d_ws, size_t ws_size,
                              hipStream_t stream) {
    const float* input_t = (const float*)d_in[0];
    const float* hidden  = (const float*)d_in[1];
    const float* w_ih    = (const float*)d_in[2];
    const float* b_ih    = (const float*)d_in[3];
    const float* w_hh    = (const float*)d_in[4];
    const float* b_hh    = (const float*)d_in[5];
    const float* w_out   = (const float*)d_in[6];
    const float* b_out   = (const float*)d_in[7];
    const float* memory  = (const float*)d_in[8];
    float* out = (float*)d_out;

    __bf16* base  = (__bf16*)d_ws;
    __bf16* AB    = base;
    __bf16* wfull = base + E_AB;
    __bf16* woutB = base + E_WF;
    __bf16* comb  = base + E_COMB;
    __bf16* ugsg  = base + E_UGSG;

    cast_kernel<<<4096, 256, 0, stream>>>(input_t, hidden, w_ih, w_hh, w_out, base);
    gates_gemm<<<dim3(64, 8), 256, 0, stream>>>(AB, wfull, b_ih, b_hh, comb, ugsg);
    attn_kernel<<<4096, 256, 0, stream>>>(input_t, memory, comb);
    out_gemm<<<dim3(128, 4), 256, 0, stream>>>(comb, woutB, b_out, ugsg, hidden, out);
}

// Round 6
// 204.117 us; speedup vs baseline: 1.4986x; 1.2426x over previous
//
#include <hip/hip_runtime.h>
#include <stdint.h>

#define B_N 16384
#define H_N 256
#define IN_W 258
#define GX_N 70
#define GY_N 70
#define SW_N 2
#define KK_N 25

typedef __bf16 bf16x8 __attribute__((ext_vector_type(8)));
typedef __bf16 bf16x4 __attribute__((ext_vector_type(4)));
typedef __bf16 bf16x2 __attribute__((ext_vector_type(2)));
typedef float f32x4 __attribute__((ext_vector_type(4)));
typedef float f32x2 __attribute__((ext_vector_type(2)));

#define AS1 __attribute__((address_space(1)))
#define AS3 __attribute__((address_space(3)))

static __device__ __forceinline__ void gload16(const void* g, void* l) {
    __builtin_amdgcn_global_load_lds((const AS1 uint32_t*)g, (AS3 uint32_t*)l, 16, 0, 0);
}

// ---- ws layout (bf16 elements) ----
// AB    at 0        : [16384][512]  ([feat|hid])            16 MB
// wfull at 8388608  : [1024][512]   rows j=c*256+col, c in {r,i,s,n};
//                     k<256 -> wih[base_c+col][k], k>=256 -> whh[base_c+col][k-256]
//                     base_c = {0,256,768,512}
// woutB at 8912896  : [256][512]
// comb  at 9043968  : [16384][512]  ([mix|q])               16 MB
// ugsg  at 17432576 : [16384][256][2] (ug,sg interleaved)   16 MB
#define E_AB   8388608ULL
#define E_WF   8912896ULL
#define E_WOUT 9043968ULL
#define E_COMB 9043968ULL
#define E_UGSG 17432576ULL

__global__ __launch_bounds__(256) void cast_kernel(
    const float* __restrict__ in_t, const float* __restrict__ hid,
    const float* __restrict__ wih, const float* __restrict__ whh,
    const float* __restrict__ wout, __bf16* __restrict__ dst)
{
    size_t g = (size_t)blockIdx.x * blockDim.x + threadIdx.x;
    size_t stride = (size_t)gridDim.x * blockDim.x;
    for (size_t e = g * 4; e < E_WOUT; e += stride * 4) {
        bf16x4 o;
        if (e < E_AB) {
            size_t row = e >> 9;
            size_t c = e & 511;
            if (c < 256) {
                // in_t row stride 258 f32 = 1032 B (8B-aligned); c%4==0 -> 8B-aligned
                const f32x2* s2 = reinterpret_cast<const f32x2*>(in_t + row * IN_W + c);
                f32x2 a = s2[0], b = s2[1];
                o.x = (__bf16)a.x; o.y = (__bf16)a.y;
                o.z = (__bf16)b.x; o.w = (__bf16)b.y;
            } else {
                f32x4 v = *reinterpret_cast<const f32x4*>(hid + row * 256 + (c - 256));
                o.x = (__bf16)v.x; o.y = (__bf16)v.y;
                o.z = (__bf16)v.z; o.w = (__bf16)v.w;
            }
        } else if (e < E_WF) {
            size_t off = e - E_AB;
            size_t j = off >> 9;       // 0..1023
            size_t k = off & 511;
            size_t c = j >> 8;         // 0..3
            size_t col = j & 255;
            size_t base = (c == 0) ? 0 : (c == 1) ? 256 : (c == 2) ? 768 : 512;
            const float* srcm = (k < 256) ? wih : whh;
            f32x4 v = *reinterpret_cast<const f32x4*>(srcm + (base + col) * 256 + (k & 255));
            o.x = (__bf16)v.x; o.y = (__bf16)v.y;
            o.z = (__bf16)v.z; o.w = (__bf16)v.w;
        } else {
            f32x4 v = *reinterpret_cast<const f32x4*>(wout + (e - E_WF));
            o.x = (__bf16)v.x; o.y = (__bf16)v.y;
            o.z = (__bf16)v.z; o.w = (__bf16)v.w;
        }
        *reinterpret_cast<bf16x4*>(dst + e) = o;
    }
}

// Fused gates GEMM, K=512 concat form. Round-2 proven 2-phase dbuf
// pipeline on a SPILL-FREE tile: block = 128 rows x 128 cols (32 hcols
// x 4 gates), 4 waves, wave = 32 rows x 128 cols -> acc = 20 f32x4 =
// 80 regs (round-2's 256-row tile needed 160 -> spilled under the
// (256,2) cap of 120; WRITE_SIZE 34MB vs 24MB true = scratch evidence).
// LDS 32KB (2 x (8KB A + 8KB B)) -> up to 4 blocks/CU (grid 1024 = 4/CU)
// so the per-step barrier drain hides under other resident blocks (m114).
// Per wave-step: 10 ds_read_b128 (2 A + 8 B), 16 MFMA.
// acc[rh][c*2+hh] gates r,i,s over K=512; n-gate split: accni k<256
// (feat@wih_n), accnh k>=256 (hid@whh_n).
__global__ __launch_bounds__(256, 2) void gates_gemm(
    const __bf16* __restrict__ AB, const __bf16* __restrict__ wfull,
    const float* __restrict__ b_ih, const float* __restrict__ b_hh,
    __bf16* __restrict__ comb, __bf16* __restrict__ ugsg)
{
    __shared__ __bf16 ldsA[2][4096];   // [buf][seg(4)][row(128)][8]
    __shared__ __bf16 ldsB[2][4096];   // [buf][seg(4)][brow(128)][8]
    const int t = threadIdx.x;
    const int lane = t & 63, w = t >> 6;
    const int lr = lane & 15, seg = lane >> 4;
    const int rb = blockIdx.x * 128;
    const int h0 = blockIdx.y * 32;

    // staging: 512 slots/buffer (seg-major: slot u = seg*128 + row);
    // thread t owns u = t (segs 0-1) and u = t+256 (segs 2-3).
    const int rA = t & 127;
    const int sA = t >> 7;             // 0..1
    const __bf16* gAt = AB + (size_t)(rb + rA) * 512 + sA * 8;   // +16 for seg+2
    const int bc = rA >> 5, bcol = rA & 31;  // brow = bc*32+bcol -> wfull row
    const __bf16* gBt = wfull + (size_t)(bc * 256 + h0 + bcol) * 512 + sA * 8;
    __bf16* lA0 = &ldsA[0][t * 8];
    __bf16* lA1 = &ldsA[1][t * 8];
    __bf16* lB0 = &ldsB[0][t * 8];
    __bf16* lB1 = &ldsB[1][t * 8];

    f32x4 acc[2][6], accni[2][2], accnh[2][2];
#pragma unroll
    for (int rh = 0; rh < 2; rh++) {
#pragma unroll
        for (int cn = 0; cn < 6; cn++) acc[rh][cn] = (f32x4){0.f, 0.f, 0.f, 0.f};
        accni[rh][0] = (f32x4){0.f, 0.f, 0.f, 0.f};
        accni[rh][1] = (f32x4){0.f, 0.f, 0.f, 0.f};
        accnh[rh][0] = (f32x4){0.f, 0.f, 0.f, 0.f};
        accnh[rh][1] = (f32x4){0.f, 0.f, 0.f, 0.f};
    }

    // prologue: stage tile 0 into buf 0
    gload16(gAt + 0, lA0);
    gload16(gAt + 16, lA0 + 2048);
    gload16(gBt + 0, lB0);
    gload16(gBt + 16, lB0 + 2048);
    __syncthreads();   // implicit vmcnt(0)

#pragma unroll 1
    for (int tt = 0; tt < 16; tt++) {
        const int cur = tt & 1;
        if (tt < 15) {   // issue next tile's stage BEFORE compute
            const int kn = (tt + 1) * 32;
            __bf16* la = cur ? lA0 : lA1;
            __bf16* lb = cur ? lB0 : lB1;
            gload16(gAt + kn, la);
            gload16(gAt + kn + 16, la + 2048);
            gload16(gBt + kn, lb);
            gload16(gBt + kn + 16, lb + 2048);
        }
        const __bf16* cA = ldsA[cur];
        const __bf16* cB = ldsB[cur];
        bf16x8 af[2];
#pragma unroll
        for (int rh = 0; rh < 2; rh++)
            af[rh] = *reinterpret_cast<const bf16x8*>(cA + seg * 1024 + (w * 32 + rh * 16 + lr) * 8);
#pragma unroll
        for (int cn = 0; cn < 6; cn++) {
            const int c = cn >> 1, hh = cn & 1;
            bf16x8 bb = *reinterpret_cast<const bf16x8*>(cB + seg * 1024 + (c * 32 + hh * 16 + lr) * 8);
#pragma unroll
            for (int rh = 0; rh < 2; rh++)
                acc[rh][(c << 1) + hh] = __builtin_amdgcn_mfma_f32_16x16x32_bf16(af[rh], bb, acc[rh][(c << 1) + hh], 0, 0, 0);
        }
        bf16x8 b6 = *reinterpret_cast<const bf16x8*>(cB + seg * 1024 + (96 + lr) * 8);
        bf16x8 b7 = *reinterpret_cast<const bf16x8*>(cB + seg * 1024 + (112 + lr) * 8);
        if (tt < 8) {
#pragma unroll
            for (int rh = 0; rh < 2; rh++) {
                accni[rh][0] = __builtin_amdgcn_mfma_f32_16x16x32_bf16(af[rh], b6, accni[rh][0], 0, 0, 0);
                accni[rh][1] = __builtin_amdgcn_mfma_f32_16x16x32_bf16(af[rh], b7, accni[rh][1], 0, 0, 0);
            }
        } else {
#pragma unroll
            for (int rh = 0; rh < 2; rh++) {
                accnh[rh][0] = __builtin_amdgcn_mfma_f32_16x16x32_bf16(af[rh], b6, accnh[rh][0], 0, 0, 0);
                accnh[rh][1] = __builtin_amdgcn_mfma_f32_16x16x32_bf16(af[rh], b7, accnh[rh][1], 0, 0, 0);
            }
        }
        __syncthreads();   // vmcnt(0): next tile landed; lgkm: reads done
    }

#pragma unroll
    for (int hh = 0; hh < 2; hh++) {
        const int col = h0 + hh * 16 + lr;
        const float br_ = b_ih[col] + b_hh[col];
        const float bi_ = b_ih[col + 256] + b_hh[col + 256];
        const float bs_ = b_ih[col + 768] + b_hh[col + 768];
        const float bni = b_ih[col + 512];
        const float bnh = b_hh[col + 512];
#pragma unroll
        for (int rh = 0; rh < 2; rh++) {
#pragma unroll
            for (int r = 0; r < 4; r++) {
                const int row = rb + w * 32 + rh * 16 + seg * 4 + r;
                float sr = acc[rh][hh][r] + br_;
                float si = acc[rh][2 + hh][r] + bi_;
                float ss = acc[rh][4 + hh][r] + bs_;
                float vni = accni[rh][hh][r] + bni;
                float vnh = accnh[rh][hh][r] + bnh;
                float rg = 1.f / (1.f + __expf(-sr));
                float ug = 1.f / (1.f + __expf(-si));
                float sg = 1.f / (1.f + __expf(-ss));
                float ng = tanhf(vni + rg * vnh);
                comb[(size_t)row * 512 + 256 + col] = (__bf16)ng;
                bf16x2 us;
                us.x = (__bf16)ug;
                us.y = (__bf16)sg;
                *reinterpret_cast<bf16x2*>(ugsg + ((size_t)row * 256 + col) * 2) = us;
            }
        }
    }
}

// Attention: one wave per row, online softmax, float4 per lane (h = 4*lane..4*lane+3).
__global__ __launch_bounds__(256) void attn_kernel(
    const float* __restrict__ in_t, const float* __restrict__ memory,
    __bf16* __restrict__ comb)
{
    const int w = threadIdx.x >> 6;
    const int lane = threadIdx.x & 63;
    const int b = blockIdx.x * 4 + w;
    const float* row_in = in_t + (size_t)b * IN_W;
    int gx = (int)row_in[256] + SW_N;
    int gy = (int)row_in[257] + SW_N;
    gx = min(max(gx, 0), GX_N - 1);
    gy = min(max(gy, 0), GY_N - 1);

    bf16x4 qb = *reinterpret_cast<const bf16x4*>(comb + (size_t)b * 512 + 256 + lane * 4);
    float q0 = (float)qb.x, q1 = (float)qb.y, q2 = (float)qb.z, q3 = (float)qb.w;

    float m = -INFINITY, d = 0.f;
    float o0 = 0.f, o1 = 0.f, o2 = 0.f, o3 = 0.f;
#pragma unroll
    for (int k = 0; k < KK_N; k++) {
        int i = k / 5, j = k % 5;
        int xi = min(max(gx + i - SW_N, 0), GX_N - 1);
        int yj = min(max(gy + j - SW_N, 0), GY_N - 1);
        const f32x4* cp = reinterpret_cast<const f32x4*>(memory + ((size_t)xi * GY_N + yj) * H_N);
        f32x4 v = cp[lane];
        float p = q0 * v.x + q1 * v.y + q2 * v.z + q3 * v.w;
        for (int off = 32; off; off >>= 1) p += __shfl_xor(p, off, 64);
        float a = (p == 0.f) ? -INFINITY : p;
        float mn = fmaxf(m, a);
        if (mn != -INFINITY) {
            float alpha = __expf(m - mn);   // m=-inf -> 0
            float e = __expf(a - mn);       // a=-inf -> 0
            d = d * alpha + e;
            o0 = o0 * alpha + e * v.x;
            o1 = o1 * alpha + e * v.y;
            o2 = o2 * alpha + e * v.z;
            o3 = o3 * alpha + e * v.w;
            m = mn;
        }
    }
    float inv = (d != 0.f) ? 1.f / d : 0.f;
    bf16x4 ob;
    ob.x = (__bf16)(o0 * inv);
    ob.y = (__bf16)(o1 * inv);
    ob.z = (__bf16)(o2 * inv);
    ob.w = (__bf16)(o3 * inv);
    *reinterpret_cast<bf16x4*>(comb + (size_t)b * 512 + lane * 4) = ob;
}

// Output GEMM (K=512) + tanh + final blend. Round-2 2-phase dbuf
// structure (tile 128x64, 4 waves, wave = 32x64). Plain launch_bounds:
// no VGPR cap -> no spill risk (acc = 8 f32x4 only).
__global__ __launch_bounds__(256) void out_gemm(
    const __bf16* __restrict__ comb, const __bf16* __restrict__ woB,
    const float* __restrict__ b_out, const __bf16* __restrict__ ugsg,
    const float* __restrict__ hidden, float* __restrict__ out)
{
    __shared__ __bf16 ldsA[2][4096];   // [buf][seg(4)][row(128)][8]
    __shared__ __bf16 ldsB[2][2048];   // [buf][seg(4)][brow(64)][8]
    const int t = threadIdx.x;
    const int lane = t & 63, w = t >> 6;
    const int lr = lane & 15, seg = lane >> 4;
    const int rb = blockIdx.x * 128;
    const int n0 = blockIdx.y * 64;

    const __bf16* gAt = comb + (size_t)(rb + (t & 127)) * 512 + ((t >> 7) << 3);
    const __bf16* gBt = woB + (size_t)(n0 + (t & 63)) * 512 + ((t >> 6) << 3);
    __bf16* lA0 = &ldsA[0][t * 8];
    __bf16* lA1 = &ldsA[1][t * 8];
    __bf16* lB0 = &ldsB[0][t * 8];
    __bf16* lB1 = &ldsB[1][t * 8];

    f32x4 acc[2][4];
#pragma unroll
    for (int rh = 0; rh < 2; rh++)
#pragma unroll
        for (int ct = 0; ct < 4; ct++) acc[rh][ct] = (f32x4){0.f, 0.f, 0.f, 0.f};

    // prologue: tile 0 -> buf 0
    gload16(gAt + 0, lA0);
    gload16(gAt + 16, lA0 + 2048);
    gload16(gBt + 0, lB0);
    __syncthreads();

#pragma unroll 1
    for (int tt = 0; tt < 16; tt++) {
        const int cur = tt & 1;
        if (tt < 15) {
            const int kn = (tt + 1) * 32;
            __bf16* la = cur ? lA0 : lA1;
            __bf16* lb = cur ? lB0 : lB1;
            gload16(gAt + kn, la);
            gload16(gAt + kn + 16, la + 2048);
            gload16(gBt + kn, lb);
        }
        const __bf16* cA = ldsA[cur];
        const __bf16* cB = ldsB[cur];
        bf16x8 af[2];
#pragma unroll
        for (int rh = 0; rh < 2; rh++)
            af[rh] = *reinterpret_cast<const bf16x8*>(cA + seg * 1024 + (w * 32 + rh * 16 + lr) * 8);
#pragma unroll
        for (int ct = 0; ct < 4; ct++) {
            bf16x8 bb = *reinterpret_cast<const bf16x8*>(cB + seg * 512 + (ct * 16 + lr) * 8);
#pragma unroll
            for (int rh = 0; rh < 2; rh++)
                acc[rh][ct] = __builtin_amdgcn_mfma_f32_16x16x32_bf16(af[rh], bb, acc[rh][ct], 0, 0, 0);
        }
        __syncthreads();
    }

#pragma unroll
    for (int ct = 0; ct < 4; ct++) {
        int col = n0 + ct * 16 + lr;
        float bo = b_out[col];
#pragma unroll
        for (int rh = 0; rh < 2; rh++) {
#pragma unroll
            for (int r = 0; r < 4; r++) {
                int row = rb + w * 32 + rh * 16 + seg * 4 + r;
                size_t idx = (size_t)row * 256 + col;
                float acs = tanhf(acc[rh][ct][r] + bo);
                float ng = (float)comb[(size_t)row * 512 + 256 + col];
                bf16x2 us = *reinterpret_cast<const bf16x2*>(ugsg + idx * 2);
                float ug = (float)us.x, sg = (float)us.y;
                float curr = ng + sg * acs;
                out[idx] = curr + ug * (hidden[idx] - curr);
            }
        }
    }
}

extern "C" void kernel_launch(void* const* d_in, const int* in_sizes, int n_in,
                              void* d_out, int out_size, void* d_ws, size_t ws_size,
                              hipStream_t stream) {
    const float* input_t = (const float*)d_in[0];
    const float* hidden  = (const float*)d_in[1];
    const float* w_ih    = (const float*)d_in[2];
    const float* b_ih    = (const float*)d_in[3];
    const float* w_hh    = (const float*)d_in[4];
    const float* b_hh    = (const float*)d_in[5];
    const float* w_out   = (const float*)d_in[6];
    const float* b_out   = (const float*)d_in[7];
    const float* memory  = (const float*)d_in[8];
    float* out = (float*)d_out;

    __bf16* base  = (__bf16*)d_ws;
    __bf16* AB    = base;
    __bf16* wfull = base + E_AB;
    __bf16* woutB = base + E_WF;
    __bf16* comb  = base + E_COMB;
    __bf16* ugsg  = base + E_UGSG;

    cast_kernel<<<4096, 256, 0, stream>>>(input_t, hidden, w_ih, w_hh, w_out, base);
    gates_gemm<<<dim3(128, 8), 256, 0, stream>>>(AB, wfull, b_ih, b_hh, comb, ugsg);
    attn_kernel<<<4096, 256, 0, stream>>>(input_t, memory, comb);
    out_gemm<<<dim3(128, 4), 256, 0, stream>>>(comb, woutB, b_out, ugsg, hidden, out);
}